// Round 1
// baseline (927.222 us; speedup 1.0000x reference)
//
#include <hip/hip_runtime.h>
#include <math.h>

#define BB 32
#define NN 64
#define PP 4
#define HH 300

__device__ __forceinline__ float eluf(float x) {
    return x > 0.0f ? x : (__expf(x) - 1.0f);
}

// ---------------------------------------------------------------------------
// Edge path: rel_logits[b,m] = sum_n dist[b,n] * sum_k w_rel[k] *
//                   elu( (edge_attr[b,m,n,:] @ W_e[:,k]) * instr[b,k] )
//                 + node_mask[b,m]
// One block per (b,m): GEMM tile A(64 rows of n x 300 h) @ W(300 x 300),
// k tiled by 64 (5 tiles), 4x4 register micro-tile per thread.
// ---------------------------------------------------------------------------
extern "C" __global__ __launch_bounds__(256)
void edge_kernel(const float* __restrict__ edge_attr,
                 const float* __restrict__ instr,
                 const float* __restrict__ dist,
                 const float* __restrict__ node_mask,
                 const float* __restrict__ w_edge,
                 const float* __restrict__ w_rel,
                 float* __restrict__ rel_logits)
{
    extern __shared__ float smem[];
    float* As = smem;             // [64][300]
    float* Ws = smem + NN * HH;   // [300][64]  one k-tile

    const int b   = blockIdx.x / NN;
    const int m   = blockIdx.x % NN;
    const int tid = (int)threadIdx.x;
    const int tx  = tid & 15;   // 16 col groups (4 cols each)
    const int ty  = tid >> 4;   // 16 row groups (4 rows each)

    // Stage A = edge_attr[b][m][:][:]  (64*300 contiguous floats)
    {
        const float4* src = reinterpret_cast<const float4*>(
            edge_attr + (size_t)(b * NN + m) * (NN * HH));
        float4* dst = reinterpret_cast<float4*>(As);
#pragma unroll 1
        for (int i = tid; i < NN * HH / 4; i += 256) dst[i] = src[i];
    }

    float s0 = 0.f, s1 = 0.f, s2 = 0.f, s3 = 0.f;  // per-thread row partials

    for (int kt = 0; kt < 5; ++kt) {
        __syncthreads();   // A staged / previous tile's reads done
        // Stage W tile: Ws[h][c] = w_edge[h][kt*64 + c]
        {
            float4* dst = reinterpret_cast<float4*>(Ws);
#pragma unroll 1
            for (int i = tid; i < HH * 16; i += 256) {   // 4800 quads
                int h  = i >> 4;
                int k0 = kt * 64 + ((i & 15) << 2);
                float4 v = make_float4(0.f, 0.f, 0.f, 0.f);
                if (k0 + 3 < HH)   // quads never straddle the 300 boundary
                    v = *reinterpret_cast<const float4*>(w_edge + h * HH + k0);
                dst[i] = v;
            }
        }
        __syncthreads();

        float acc[4][4] = {{0.f, 0.f, 0.f, 0.f}, {0.f, 0.f, 0.f, 0.f},
                           {0.f, 0.f, 0.f, 0.f}, {0.f, 0.f, 0.f, 0.f}};
        const float4* A4 = reinterpret_cast<const float4*>(As);
        const float4* W4 = reinterpret_cast<const float4*>(Ws);
        const float4* Ar0 = A4 + (4 * ty + 0) * 75;
        const float4* Ar1 = A4 + (4 * ty + 1) * 75;
        const float4* Ar2 = A4 + (4 * ty + 2) * 75;
        const float4* Ar3 = A4 + (4 * ty + 3) * 75;

#define FMA_ROW(i, A)                                                                                 \
    acc[i][0] = fmaf((A).x, w0.x, fmaf((A).y, w1.x, fmaf((A).z, w2.x, fmaf((A).w, w3.x, acc[i][0])))); \
    acc[i][1] = fmaf((A).x, w0.y, fmaf((A).y, w1.y, fmaf((A).z, w2.y, fmaf((A).w, w3.y, acc[i][1])))); \
    acc[i][2] = fmaf((A).x, w0.z, fmaf((A).y, w1.z, fmaf((A).z, w2.z, fmaf((A).w, w3.z, acc[i][2])))); \
    acc[i][3] = fmaf((A).x, w0.w, fmaf((A).y, w1.w, fmaf((A).z, w2.w, fmaf((A).w, w3.w, acc[i][3]))));

#pragma unroll 5
        for (int hq = 0; hq < 75; ++hq) {      // 4 h per iter, 300 total
            float4 a0 = Ar0[hq];
            float4 a1 = Ar1[hq];
            float4 a2 = Ar2[hq];
            float4 a3 = Ar3[hq];
            float4 w0 = W4[(hq * 4 + 0) * 16 + tx];
            float4 w1 = W4[(hq * 4 + 1) * 16 + tx];
            float4 w2 = W4[(hq * 4 + 2) * 16 + tx];
            float4 w3 = W4[(hq * 4 + 3) * 16 + tx];
            FMA_ROW(0, a0)
            FMA_ROW(1, a1)
            FMA_ROW(2, a2)
            FMA_ROW(3, a3)
        }
#undef FMA_ROW

        // Fused epilogue: val = elu(acc * instr[k]) * w_rel[k], accumulate per row
        int k0 = kt * 64 + (tx << 2);
        if (k0 + 3 < HH) {
            float4 iv = *reinterpret_cast<const float4*>(instr + b * HH + k0);
            float4 wr = *reinterpret_cast<const float4*>(w_rel + k0);
            s0 += eluf(acc[0][0] * iv.x) * wr.x + eluf(acc[0][1] * iv.y) * wr.y +
                  eluf(acc[0][2] * iv.z) * wr.z + eluf(acc[0][3] * iv.w) * wr.w;
            s1 += eluf(acc[1][0] * iv.x) * wr.x + eluf(acc[1][1] * iv.y) * wr.y +
                  eluf(acc[1][2] * iv.z) * wr.z + eluf(acc[1][3] * iv.w) * wr.w;
            s2 += eluf(acc[2][0] * iv.x) * wr.x + eluf(acc[2][1] * iv.y) * wr.y +
                  eluf(acc[2][2] * iv.z) * wr.z + eluf(acc[2][3] * iv.w) * wr.w;
            s3 += eluf(acc[3][0] * iv.x) * wr.x + eluf(acc[3][1] * iv.y) * wr.y +
                  eluf(acc[3][2] * iv.z) * wr.z + eluf(acc[3][3] * iv.w) * wr.w;
        }
    }

    // Reduce row partials over the 16 tx lanes (lanes are 16-aligned groups)
#pragma unroll
    for (int msk = 1; msk < 16; msk <<= 1) {
        s0 += __shfl_xor(s0, msk);
        s1 += __shfl_xor(s1, msk);
        s2 += __shfl_xor(s2, msk);
        s3 += __shfl_xor(s3, msk);
    }
    __syncthreads();   // everyone done reading As before reuse
    if (tx == 0) {
        As[4 * ty + 0] = s0;
        As[4 * ty + 1] = s1;
        As[4 * ty + 2] = s2;
        As[4 * ty + 3] = s3;
    }
    __syncthreads();
    if (tid < 64) {
        float v = As[tid] * dist[b * NN + tid];
#pragma unroll
        for (int msk = 1; msk < 64; msk <<= 1) v += __shfl_xor(v, msk);
        if (tid == 0) rel_logits[b * NN + m] = v + node_mask[b * NN + m];
    }
}

// ---------------------------------------------------------------------------
// Node path: state_logits[b,n] = sum_k w_state[k] *
//     elu( instr[b,k] * sum_{p,h} node_attr[b,n,p,h]*sim[b,p]*W_np[p,h,k] )
//   + node_mask[b,n]
// One block per (b, 8 rows of n). A rows (8x1200, sim folded) in LDS,
// W streamed from L2 (1.44 MB working set, L2-resident).
// ---------------------------------------------------------------------------
extern "C" __global__ __launch_bounds__(256)
void node_kernel(const float* __restrict__ node_attr,
                 const float* __restrict__ instr,
                 const float* __restrict__ sim,
                 const float* __restrict__ node_mask,
                 const float* __restrict__ w_np,
                 const float* __restrict__ w_state,
                 float* __restrict__ state_logits)
{
    __shared__ float As[8 * 1200];
    const int b   = (int)blockIdx.x >> 3;
    const int n0  = ((int)blockIdx.x & 7) * 8;
    const int tid = (int)threadIdx.x;
    const int tx  = tid & 31;   // cols c = 4*tx in [0,128)
    const int r   = tid >> 5;   // row 0..7

    {
        const float4* src = reinterpret_cast<const float4*>(
            node_attr + (size_t)(b * NN + n0) * (PP * HH));
        float4* dst = reinterpret_cast<float4*>(As);
#pragma unroll 1
        for (int i = tid; i < 8 * 1200 / 4; i += 256) {
            float4 v = src[i];
            int p = (i % 300) / 75;          // 300 quads/row, 75 per p
            float s = sim[b * PP + p];
            v.x *= s; v.y *= s; v.z *= s; v.w *= s;
            dst[i] = v;
        }
    }
    __syncthreads();

    float spart = 0.f;
    const float4* A4 = reinterpret_cast<const float4*>(As) + r * 300;

#pragma unroll 1
    for (int ct = 0; ct < 3; ++ct) {        // col tiles of 128: 128,128,44
        int k0 = ct * 128 + (tx << 2);
        if (k0 + 3 >= HH) continue;          // quads never straddle 300
        float acc0 = 0.f, acc1 = 0.f, acc2 = 0.f, acc3 = 0.f;
#pragma unroll 2
        for (int hq = 0; hq < 300; ++hq) {   // 1200 h' in quads of 4
            float4 a = A4[hq];
            const float* wb = w_np + (size_t)(hq * 4) * HH + k0;
            float4 w0 = *reinterpret_cast<const float4*>(wb);
            float4 w1 = *reinterpret_cast<const float4*>(wb + HH);
            float4 w2 = *reinterpret_cast<const float4*>(wb + 2 * HH);
            float4 w3 = *reinterpret_cast<const float4*>(wb + 3 * HH);
            acc0 = fmaf(a.x, w0.x, fmaf(a.y, w1.x, fmaf(a.z, w2.x, fmaf(a.w, w3.x, acc0))));
            acc1 = fmaf(a.x, w0.y, fmaf(a.y, w1.y, fmaf(a.z, w2.y, fmaf(a.w, w3.y, acc1))));
            acc2 = fmaf(a.x, w0.z, fmaf(a.y, w1.z, fmaf(a.z, w2.z, fmaf(a.w, w3.z, acc2))));
            acc3 = fmaf(a.x, w0.w, fmaf(a.y, w1.w, fmaf(a.z, w2.w, fmaf(a.w, w3.w, acc3))));
        }
        float4 iv  = *reinterpret_cast<const float4*>(instr + b * HH + k0);
        float4 wsv = *reinterpret_cast<const float4*>(w_state + k0);
        spart += eluf(acc0 * iv.x) * wsv.x + eluf(acc1 * iv.y) * wsv.y +
                 eluf(acc2 * iv.z) * wsv.z + eluf(acc3 * iv.w) * wsv.w;
    }

#pragma unroll
    for (int msk = 1; msk < 32; msk <<= 1) spart += __shfl_xor(spart, msk);
    if (tx == 0)
        state_logits[b * NN + n0 + r] = spart + node_mask[b * NN + n0 + r];
}

// ---------------------------------------------------------------------------
// Final: softmax both logit sets over n (64 lanes = 1 wave per b) and blend.
// ---------------------------------------------------------------------------
extern "C" __global__ __launch_bounds__(64)
void final_kernel(const float* __restrict__ rel_logits,
                  const float* __restrict__ state_logits,
                  const float* __restrict__ rel_sim,
                  float* __restrict__ out)
{
    const int b = (int)blockIdx.x;
    const int n = (int)threadIdx.x;
    float sl = state_logits[b * NN + n];
    float rl = rel_logits[b * NN + n];

    float ms = sl, mr = rl;
#pragma unroll
    for (int msk = 1; msk < 64; msk <<= 1) {
        ms = fmaxf(ms, __shfl_xor(ms, msk));
        mr = fmaxf(mr, __shfl_xor(mr, msk));
    }
    float es = __expf(sl - ms);
    float er = __expf(rl - mr);
    float ss = es, sr = er;
#pragma unroll
    for (int msk = 1; msk < 64; msk <<= 1) {
        ss += __shfl_xor(ss, msk);
        sr += __shfl_xor(sr, msk);
    }
    float rr = rel_sim[b];
    out[b * NN + n] = rr * (er / sr) + (1.f - rr) * (es / ss);
}

extern "C" void kernel_launch(void* const* d_in, const int* in_sizes, int n_in,
                              void* d_out, int out_size, void* d_ws, size_t ws_size,
                              hipStream_t stream) {
    const float* node_attr    = (const float*)d_in[0];
    const float* edge_attr    = (const float*)d_in[1];
    const float* instruction  = (const float*)d_in[2];
    const float* distribution = (const float*)d_in[3];
    const float* node_sim     = (const float*)d_in[4];
    const float* rel_sim      = (const float*)d_in[5];
    const float* node_mask    = (const float*)d_in[6];
    const float* w_np         = (const float*)d_in[7];
    const float* w_edge       = (const float*)d_in[8];
    const float* w_state      = (const float*)d_in[9];
    const float* w_rel        = (const float*)d_in[10];
    float* out = (float*)d_out;

    float* rel_ws   = (float*)d_ws;          // [B*N]
    float* state_ws = rel_ws + BB * NN;      // [B*N]

    const size_t smem_edge = (size_t)(NN * HH + HH * 64) * sizeof(float);  // 153.6 KB
    static_assert((NN * HH + HH * 64) * sizeof(float) <= 160 * 1024, "LDS");
    hipFuncSetAttribute(reinterpret_cast<const void*>(edge_kernel),
                        hipFuncAttributeMaxDynamicSharedMemorySize,
                        (int)smem_edge);

    edge_kernel<<<dim3(BB * NN), dim3(256), smem_edge, stream>>>(
        edge_attr, instruction, distribution, node_mask, w_edge, w_rel, rel_ws);

    node_kernel<<<dim3(BB * 8), dim3(256), 0, stream>>>(
        node_attr, instruction, node_sim, node_mask, w_np, w_state, state_ws);

    final_kernel<<<dim3(BB), dim3(64), 0, stream>>>(
        rel_ws, state_ws, rel_sim, out);
}

// Round 2
// 328.184 us; speedup vs baseline: 2.8253x; 2.8253x over previous
//
#include <hip/hip_runtime.h>
#include <math.h>

#define BB 32
#define NN 64
#define PP 4
#define HH 300

#define NKK 10   // h (reduction) steps: ceil(300/32) -> padded to 320
#define NCT 19   // output k col-tiles of 16: ceil(300/16)

typedef float f32x4  __attribute__((ext_vector_type(4)));
typedef short bf16x8 __attribute__((ext_vector_type(8)));

__device__ __forceinline__ float eluf(float x) {
    return x > 0.0f ? x : (__expf(x) - 1.0f);
}

// round-to-nearest-even fp32 -> bf16 bits
__device__ __forceinline__ unsigned short f2bf(float x) {
    unsigned u = __float_as_uint(x);
    u += 0x7FFFu + ((u >> 16) & 1u);
    return (unsigned short)(u >> 16);
}
__device__ __forceinline__ float bf2f(unsigned short s) {
    return __uint_as_float(((unsigned)s) << 16);
}

// ---------------------------------------------------------------------------
// Pre-convert W_edge (300x300 fp32) into MFMA B-fragment-linear bf16 hi/lo:
// fragment tile (kk, ct): lane l, elem j holds W[h][k],
//   h = kk*32 + (l>>4)*8 + j, k = ct*16 + (l&15); zero-padded outside 300.
// ---------------------------------------------------------------------------
extern "C" __global__ __launch_bounds__(64)
void wprep_kernel(const float* __restrict__ w_edge,
                  short* __restrict__ w_hi, short* __restrict__ w_lo)
{
    const int tile = (int)blockIdx.x;          // kk*NCT + ct
    const int kk = tile / NCT, ct = tile % NCT;
    const int lane = (int)threadIdx.x;
    const int h0 = kk * 32 + (lane >> 4) * 8;
    const int k  = ct * 16 + (lane & 15);
    const size_t base = ((size_t)tile * 64 + lane) * 8;
#pragma unroll
    for (int j = 0; j < 8; ++j) {
        int h = h0 + j;
        float v = (h < HH && k < HH) ? w_edge[h * HH + k] : 0.f;
        unsigned short hb = f2bf(v);
        unsigned short lb = f2bf(v - bf2f(hb));
        w_hi[base + j] = (short)hb;
        w_lo[base + j] = (short)lb;
    }
}

// ---------------------------------------------------------------------------
// Edge path via MFMA, 3-pass bf16 split (fp32-grade accuracy):
//   rel_logits[b,m] = sum_{n,k} dist[b,n]*w_rel[k]*
//                     elu( (edge_attr[b,m,n,:]@W)[k] * instr[b,k] ) + mask
// One block per (b,m); wave w owns n-rows [16w,16w+16). A-fragments loaded
// once from global into registers (no LDS staging); B-fragments from the
// precomputed fragment-linear arrays (L1/L2 resident).
// ---------------------------------------------------------------------------
extern "C" __global__ __launch_bounds__(256)
void edge_kernel(const float* __restrict__ edge_attr,
                 const float* __restrict__ instr,
                 const float* __restrict__ dist,
                 const float* __restrict__ node_mask,
                 const short* __restrict__ w_hi,
                 const short* __restrict__ w_lo,
                 const float* __restrict__ w_rel,
                 float* __restrict__ rel_logits)
{
    __shared__ float red[NN];
    const int b    = (int)blockIdx.x / NN;
    const int m    = (int)blockIdx.x % NN;
    const int tid  = (int)threadIdx.x;
    const int wv   = tid >> 6;     // wave -> n row-tile
    const int lane = tid & 63;
    const int lrow = lane & 15;    // A row within tile (load) / C col (epilogue)
    const int lgrp = lane >> 4;

    // ---- A fragments (hi/lo) into registers, read-once from global ----
    const float* arow = edge_attr
        + (size_t)((b * NN + m) * NN + wv * 16 + lrow) * HH;
    bf16x8 a_hi[NKK], a_lo[NKK];
#pragma unroll
    for (int kk = 0; kk < NKK; ++kk) {
        const int h0 = kk * 32 + lgrp * 8;
        float v[8];
        if (h0 + 7 < HH) {
            f32x4 p0 = *reinterpret_cast<const f32x4*>(arow + h0);
            f32x4 p1 = *reinterpret_cast<const f32x4*>(arow + h0 + 4);
            v[0] = p0[0]; v[1] = p0[1]; v[2] = p0[2]; v[3] = p0[3];
            v[4] = p1[0]; v[5] = p1[1]; v[6] = p1[2]; v[7] = p1[3];
        } else {
#pragma unroll
            for (int j = 0; j < 8; ++j)
                v[j] = (h0 + j < HH) ? arow[h0 + j] : 0.f;
        }
#pragma unroll
        for (int j = 0; j < 8; ++j) {
            unsigned short hb = f2bf(v[j]);
            a_hi[kk][j] = (short)hb;
            a_lo[kk][j] = (short)f2bf(v[j] - bf2f(hb));
        }
    }

    const bf16x8* WH = reinterpret_cast<const bf16x8*>(w_hi);
    const bf16x8* WL = reinterpret_cast<const bf16x8*>(w_lo);
    const int binst = b * HH;

    float rs0 = 0.f, rs1 = 0.f, rs2 = 0.f, rs3 = 0.f;  // 4 C-rows per lane

#pragma unroll 1
    for (int ct = 0; ct < NCT; ++ct) {
        f32x4 acc = {0.f, 0.f, 0.f, 0.f};
#pragma unroll
        for (int kk = 0; kk < NKK; ++kk) {
            bf16x8 bh = WH[(kk * NCT + ct) * 64 + lane];
            bf16x8 bl = WL[(kk * NCT + ct) * 64 + lane];
            acc = __builtin_amdgcn_mfma_f32_16x16x32_bf16(a_hi[kk], bh, acc, 0, 0, 0);
            acc = __builtin_amdgcn_mfma_f32_16x16x32_bf16(a_lo[kk], bh, acc, 0, 0, 0);
            acc = __builtin_amdgcn_mfma_f32_16x16x32_bf16(a_hi[kk], bl, acc, 0, 0, 0);
        }
        // epilogue: this lane's col k = ct*16 + lrow, rows = lgrp*4 + i
        const int k  = ct * 16 + lrow;
        const bool ok = k < HH;
        const int kc = ok ? k : (HH - 1);
        const float iv = instr[binst + kc];
        const float wr = ok ? w_rel[kc] : 0.f;
        rs0 += eluf(acc[0] * iv) * wr;
        rs1 += eluf(acc[1] * iv) * wr;
        rs2 += eluf(acc[2] * iv) * wr;
        rs3 += eluf(acc[3] * iv) * wr;
    }

    // reduce over the 16 lanes sharing the same C-rows (masks 1,2,4,8)
#pragma unroll
    for (int msk = 1; msk < 16; msk <<= 1) {
        rs0 += __shfl_xor(rs0, msk);
        rs1 += __shfl_xor(rs1, msk);
        rs2 += __shfl_xor(rs2, msk);
        rs3 += __shfl_xor(rs3, msk);
    }
    if (lrow == 0) {
        const int r0 = wv * 16 + lgrp * 4;
        red[r0 + 0] = rs0;
        red[r0 + 1] = rs1;
        red[r0 + 2] = rs2;
        red[r0 + 3] = rs3;
    }
    __syncthreads();
    if (tid < 64) {
        float v = red[tid] * dist[b * NN + tid];
#pragma unroll
        for (int msk = 1; msk < 64; msk <<= 1) v += __shfl_xor(v, msk);
        if (tid == 0) rel_logits[b * NN + m] = v + node_mask[b * NN + m];
    }
}

// ---------------------------------------------------------------------------
// Node path (unchanged fp32): state_logits[b,n] = sum_k w_state[k] *
//     elu( instr[b,k] * sum_{p,h} node_attr[b,n,p,h]*sim[b,p]*W_np[p,h,k] )
// ---------------------------------------------------------------------------
extern "C" __global__ __launch_bounds__(256)
void node_kernel(const float* __restrict__ node_attr,
                 const float* __restrict__ instr,
                 const float* __restrict__ sim,
                 const float* __restrict__ node_mask,
                 const float* __restrict__ w_np,
                 const float* __restrict__ w_state,
                 float* __restrict__ state_logits)
{
    __shared__ float As[8 * 1200];
    const int b   = (int)blockIdx.x >> 3;
    const int n0  = ((int)blockIdx.x & 7) * 8;
    const int tid = (int)threadIdx.x;
    const int tx  = tid & 31;
    const int r   = tid >> 5;

    {
        const float4* src = reinterpret_cast<const float4*>(
            node_attr + (size_t)(b * NN + n0) * (PP * HH));
        float4* dst = reinterpret_cast<float4*>(As);
#pragma unroll 1
        for (int i = tid; i < 8 * 1200 / 4; i += 256) {
            float4 v = src[i];
            int p = (i % 300) / 75;
            float s = sim[b * PP + p];
            v.x *= s; v.y *= s; v.z *= s; v.w *= s;
            dst[i] = v;
        }
    }
    __syncthreads();

    float spart = 0.f;
    const float4* A4 = reinterpret_cast<const float4*>(As) + r * 300;

#pragma unroll 1
    for (int ct = 0; ct < 3; ++ct) {
        int k0 = ct * 128 + (tx << 2);
        if (k0 + 3 >= HH) continue;
        float acc0 = 0.f, acc1 = 0.f, acc2 = 0.f, acc3 = 0.f;
#pragma unroll 2
        for (int hq = 0; hq < 300; ++hq) {
            float4 a = A4[hq];
            const float* wb = w_np + (size_t)(hq * 4) * HH + k0;
            float4 w0 = *reinterpret_cast<const float4*>(wb);
            float4 w1 = *reinterpret_cast<const float4*>(wb + HH);
            float4 w2 = *reinterpret_cast<const float4*>(wb + 2 * HH);
            float4 w3 = *reinterpret_cast<const float4*>(wb + 3 * HH);
            acc0 = fmaf(a.x, w0.x, fmaf(a.y, w1.x, fmaf(a.z, w2.x, fmaf(a.w, w3.x, acc0))));
            acc1 = fmaf(a.x, w0.y, fmaf(a.y, w1.y, fmaf(a.z, w2.y, fmaf(a.w, w3.y, acc1))));
            acc2 = fmaf(a.x, w0.z, fmaf(a.y, w1.z, fmaf(a.z, w2.z, fmaf(a.w, w3.z, acc2))));
            acc3 = fmaf(a.x, w0.w, fmaf(a.y, w1.w, fmaf(a.z, w2.w, fmaf(a.w, w3.w, acc3))));
        }
        float4 iv  = *reinterpret_cast<const float4*>(instr + b * HH + k0);
        float4 wsv = *reinterpret_cast<const float4*>(w_state + k0);
        spart += eluf(acc0 * iv.x) * wsv.x + eluf(acc1 * iv.y) * wsv.y +
                 eluf(acc2 * iv.z) * wsv.z + eluf(acc3 * iv.w) * wsv.w;
    }

#pragma unroll
    for (int msk = 1; msk < 32; msk <<= 1) spart += __shfl_xor(spart, msk);
    if (tx == 0)
        state_logits[b * NN + n0 + r] = spart + node_mask[b * NN + n0 + r];
}

// ---------------------------------------------------------------------------
// Final: softmax both logit sets over n (one wave per b) and blend.
// ---------------------------------------------------------------------------
extern "C" __global__ __launch_bounds__(64)
void final_kernel(const float* __restrict__ rel_logits,
                  const float* __restrict__ state_logits,
                  const float* __restrict__ rel_sim,
                  float* __restrict__ out)
{
    const int b = (int)blockIdx.x;
    const int n = (int)threadIdx.x;
    float sl = state_logits[b * NN + n];
    float rl = rel_logits[b * NN + n];

    float ms = sl, mr = rl;
#pragma unroll
    for (int msk = 1; msk < 64; msk <<= 1) {
        ms = fmaxf(ms, __shfl_xor(ms, msk));
        mr = fmaxf(mr, __shfl_xor(mr, msk));
    }
    float es = __expf(sl - ms);
    float er = __expf(rl - mr);
    float ss = es, sr = er;
#pragma unroll
    for (int msk = 1; msk < 64; msk <<= 1) {
        ss += __shfl_xor(ss, msk);
        sr += __shfl_xor(sr, msk);
    }
    float rr = rel_sim[b];
    out[b * NN + n] = rr * (er / sr) + (1.f - rr) * (es / ss);
}

extern "C" void kernel_launch(void* const* d_in, const int* in_sizes, int n_in,
                              void* d_out, int out_size, void* d_ws, size_t ws_size,
                              hipStream_t stream) {
    const float* node_attr    = (const float*)d_in[0];
    const float* edge_attr    = (const float*)d_in[1];
    const float* instruction  = (const float*)d_in[2];
    const float* distribution = (const float*)d_in[3];
    const float* node_sim     = (const float*)d_in[4];
    const float* rel_sim      = (const float*)d_in[5];
    const float* node_mask    = (const float*)d_in[6];
    const float* w_np         = (const float*)d_in[7];
    const float* w_edge       = (const float*)d_in[8];
    const float* w_state      = (const float*)d_in[9];
    const float* w_rel        = (const float*)d_in[10];
    float* out = (float*)d_out;

    // workspace layout (16B-aligned chunks)
    float* rel_ws   = (float*)d_ws;                         // [2048] f32
    float* state_ws = rel_ws + BB * NN;                     // [2048] f32
    char*  wsb      = (char*)d_ws;
    short* w_hi     = (short*)(wsb + 16384);                // NKK*NCT*64*8 shorts
    short* w_lo     = (short*)(wsb + 16384 + NKK * NCT * 64 * 8 * 2);

    wprep_kernel<<<dim3(NKK * NCT), dim3(64), 0, stream>>>(w_edge, w_hi, w_lo);

    edge_kernel<<<dim3(BB * NN), dim3(256), 0, stream>>>(
        edge_attr, instruction, distribution, node_mask, w_hi, w_lo, w_rel, rel_ws);

    node_kernel<<<dim3(BB * 8), dim3(256), 0, stream>>>(
        node_attr, instruction, node_sim, node_mask, w_np, w_state, state_ws);

    final_kernel<<<dim3(BB), dim3(64), 0, stream>>>(
        rel_ws, state_ws, rel_sim, out);
}

// Round 3
// 260.841 us; speedup vs baseline: 3.5547x; 1.2582x over previous
//
#include <hip/hip_runtime.h>
#include <math.h>

#define BB 32
#define NN 64
#define PP 4
#define HH 300

#define NKK 10    // edge reduction tiles: ceil(300/32)
#define NCT 19    // output col-tiles of 16: ceil(300/16)
#define NKK2 38   // node reduction tiles: ceil(1200/32)
#define CHK 10    // node kk chunk size (4 chunks cover 38)

typedef float f32x4  __attribute__((ext_vector_type(4)));
typedef short bf16x8 __attribute__((ext_vector_type(8)));

__device__ __forceinline__ float eluf(float x) {
    return x > 0.0f ? x : (__expf(x) - 1.0f);
}

// round-to-nearest-even fp32 -> bf16 bits
__device__ __forceinline__ unsigned short f2bf(float x) {
    unsigned u = __float_as_uint(x);
    u += 0x7FFFu + ((u >> 16) & 1u);
    return (unsigned short)(u >> 16);
}
__device__ __forceinline__ float bf2f(unsigned short s) {
    return __uint_as_float(((unsigned)s) << 16);
}

// ---------------------------------------------------------------------------
// Pre-convert W_edge (300x300 fp32) into MFMA B-fragment-linear bf16 hi/lo:
// tile (kk, ct): lane l, elem j holds W[h][k], h = kk*32 + (l>>4)*8 + j,
// k = ct*16 + (l&15); zero-padded outside 300.
// ---------------------------------------------------------------------------
extern "C" __global__ __launch_bounds__(64)
void wprep_kernel(const float* __restrict__ w_edge,
                  short* __restrict__ w_hi, short* __restrict__ w_lo)
{
    const int tile = (int)blockIdx.x;          // kk*NCT + ct
    const int kk = tile / NCT, ct = tile % NCT;
    const int lane = (int)threadIdx.x;
    const int h0 = kk * 32 + (lane >> 4) * 8;
    const int k  = ct * 16 + (lane & 15);
    const size_t base = ((size_t)tile * 64 + lane) * 8;
#pragma unroll
    for (int j = 0; j < 8; ++j) {
        int h = h0 + j;
        float v = (h < HH && k < HH) ? w_edge[h * HH + k] : 0.f;
        unsigned short hb = f2bf(v);
        unsigned short lb = f2bf(v - bf2f(hb));
        w_hi[base + j] = (short)hb;
        w_lo[base + j] = (short)lb;
    }
}

// Same for W_np flattened to 1200x300 (K index = p*300+h).
extern "C" __global__ __launch_bounds__(64)
void wprep2_kernel(const float* __restrict__ w_np,
                   short* __restrict__ w2_hi, short* __restrict__ w2_lo)
{
    const int tile = (int)blockIdx.x;          // kk*NCT + ct
    const int kk = tile / NCT, ct = tile % NCT;
    const int lane = (int)threadIdx.x;
    const int h0 = kk * 32 + (lane >> 4) * 8;
    const int k  = ct * 16 + (lane & 15);
    const size_t base = ((size_t)tile * 64 + lane) * 8;
#pragma unroll
    for (int j = 0; j < 8; ++j) {
        int h = h0 + j;
        float v = (h < PP * HH && k < HH) ? w_np[(size_t)h * HH + k] : 0.f;
        unsigned short hb = f2bf(v);
        unsigned short lb = f2bf(v - bf2f(hb));
        w2_hi[base + j] = (short)hb;
        w2_lo[base + j] = (short)lb;
    }
}

// ---------------------------------------------------------------------------
// Edge path via MFMA, 3-pass bf16 split (fp32-grade accuracy).
// One block per (b,m); wave wv owns n-rows [16wv,16wv+16).
// ---------------------------------------------------------------------------
extern "C" __global__ __launch_bounds__(256)
void edge_kernel(const float* __restrict__ edge_attr,
                 const float* __restrict__ instr,
                 const float* __restrict__ dist,
                 const float* __restrict__ node_mask,
                 const short* __restrict__ w_hi,
                 const short* __restrict__ w_lo,
                 const float* __restrict__ w_rel,
                 float* __restrict__ rel_logits)
{
    __shared__ float red[NN];
    const int b    = (int)blockIdx.x / NN;
    const int m    = (int)blockIdx.x % NN;
    const int tid  = (int)threadIdx.x;
    const int wv   = tid >> 6;
    const int lane = tid & 63;
    const int lrow = lane & 15;
    const int lgrp = lane >> 4;

    const float* arow = edge_attr
        + (size_t)((b * NN + m) * NN + wv * 16 + lrow) * HH;
    bf16x8 a_hi[NKK], a_lo[NKK];
#pragma unroll
    for (int kk = 0; kk < NKK; ++kk) {
        const int h0 = kk * 32 + lgrp * 8;
        float v[8];
        if (h0 + 7 < HH) {
            f32x4 p0 = *reinterpret_cast<const f32x4*>(arow + h0);
            f32x4 p1 = *reinterpret_cast<const f32x4*>(arow + h0 + 4);
            v[0] = p0[0]; v[1] = p0[1]; v[2] = p0[2]; v[3] = p0[3];
            v[4] = p1[0]; v[5] = p1[1]; v[6] = p1[2]; v[7] = p1[3];
        } else {
#pragma unroll
            for (int j = 0; j < 8; ++j)
                v[j] = (h0 + j < HH) ? arow[h0 + j] : 0.f;
        }
#pragma unroll
        for (int j = 0; j < 8; ++j) {
            unsigned short hb = f2bf(v[j]);
            a_hi[kk][j] = (short)hb;
            a_lo[kk][j] = (short)f2bf(v[j] - bf2f(hb));
        }
    }

    const bf16x8* WH = reinterpret_cast<const bf16x8*>(w_hi);
    const bf16x8* WL = reinterpret_cast<const bf16x8*>(w_lo);
    const int binst = b * HH;

    float rs0 = 0.f, rs1 = 0.f, rs2 = 0.f, rs3 = 0.f;

#pragma unroll 1
    for (int ct = 0; ct < NCT; ++ct) {
        f32x4 acc = {0.f, 0.f, 0.f, 0.f};
#pragma unroll
        for (int kk = 0; kk < NKK; ++kk) {
            bf16x8 bh = WH[(kk * NCT + ct) * 64 + lane];
            bf16x8 bl = WL[(kk * NCT + ct) * 64 + lane];
            acc = __builtin_amdgcn_mfma_f32_16x16x32_bf16(a_hi[kk], bh, acc, 0, 0, 0);
            acc = __builtin_amdgcn_mfma_f32_16x16x32_bf16(a_lo[kk], bh, acc, 0, 0, 0);
            acc = __builtin_amdgcn_mfma_f32_16x16x32_bf16(a_hi[kk], bl, acc, 0, 0, 0);
        }
        const int k  = ct * 16 + lrow;
        const bool ok = k < HH;
        const int kc = ok ? k : (HH - 1);
        const float iv = instr[binst + kc];
        const float wr = ok ? w_rel[kc] : 0.f;
        rs0 += eluf(acc[0] * iv) * wr;
        rs1 += eluf(acc[1] * iv) * wr;
        rs2 += eluf(acc[2] * iv) * wr;
        rs3 += eluf(acc[3] * iv) * wr;
    }

#pragma unroll
    for (int msk = 1; msk < 16; msk <<= 1) {
        rs0 += __shfl_xor(rs0, msk);
        rs1 += __shfl_xor(rs1, msk);
        rs2 += __shfl_xor(rs2, msk);
        rs3 += __shfl_xor(rs3, msk);
    }
    if (lrow == 0) {
        const int r0 = wv * 16 + lgrp * 4;
        red[r0 + 0] = rs0;
        red[r0 + 1] = rs1;
        red[r0 + 2] = rs2;
        red[r0 + 3] = rs3;
    }
    __syncthreads();
    if (tid < 64) {
        float v = red[tid] * dist[b * NN + tid];
#pragma unroll
        for (int msk = 1; msk < 64; msk <<= 1) v += __shfl_xor(v, msk);
        if (tid == 0) rel_logits[b * NN + m] = v + node_mask[b * NN + m];
    }
}

// ---------------------------------------------------------------------------
// Node path via MFMA: A[b,n,K=1200] (sim folded) @ Wflat[1200x300].
// One block per (b, 16-row n-tile); 4 waves split the 19 col-tiles
// (wave wv handles ct = wv, wv+4, ...). A-fragments read-once from global
// in kk-chunks of 10; fused elu/w_state epilogue; LDS cross-wave reduce.
// ---------------------------------------------------------------------------
extern "C" __global__ __launch_bounds__(256)
void node_mfma_kernel(const float* __restrict__ node_attr,
                      const float* __restrict__ instr,
                      const float* __restrict__ sim,
                      const float* __restrict__ node_mask,
                      const short* __restrict__ w2_hi,
                      const short* __restrict__ w2_lo,
                      const float* __restrict__ w_state,
                      float* __restrict__ state_logits)
{
    __shared__ float red[4][16];
    const int b    = (int)blockIdx.x >> 2;
    const int nt   = (int)blockIdx.x & 3;
    const int tid  = (int)threadIdx.x;
    const int wv   = tid >> 6;
    const int lane = tid & 63;
    const int lrow = lane & 15;
    const int lgrp = lane >> 4;

    const float* arow = node_attr
        + (size_t)(b * NN + nt * 16 + lrow) * (PP * HH);
    float sm[PP];
#pragma unroll
    for (int p = 0; p < PP; ++p) sm[p] = sim[b * PP + p];

    const bf16x8* WH = reinterpret_cast<const bf16x8*>(w2_hi);
    const bf16x8* WL = reinterpret_cast<const bf16x8*>(w2_lo);

    f32x4 acc[5] = {{0.f,0.f,0.f,0.f},{0.f,0.f,0.f,0.f},{0.f,0.f,0.f,0.f},
                    {0.f,0.f,0.f,0.f},{0.f,0.f,0.f,0.f}};

#pragma unroll 1
    for (int ch = 0; ch < 4; ++ch) {
        bf16x8 a_hi[CHK], a_lo[CHK];
#pragma unroll
        for (int q = 0; q < CHK; ++q) {
            const int kk = ch * CHK + q;
            const int h0 = kk * 32 + lgrp * 8;
            float v[8];
            if (kk < NKK2 && h0 + 7 < PP * HH) {
                f32x4 p0 = *reinterpret_cast<const f32x4*>(arow + h0);
                f32x4 p1 = *reinterpret_cast<const f32x4*>(arow + h0 + 4);
                v[0] = p0[0]; v[1] = p0[1]; v[2] = p0[2]; v[3] = p0[3];
                v[4] = p1[0]; v[5] = p1[1]; v[6] = p1[2]; v[7] = p1[3];
            } else {
#pragma unroll
                for (int j = 0; j < 8; ++j)
                    v[j] = (kk < NKK2 && h0 + j < PP * HH) ? arow[h0 + j] : 0.f;
            }
#pragma unroll
            for (int j = 0; j < 8; ++j) {
                const int h = h0 + j;
                const int p = (h < PP * HH) ? (h / HH) : 0;
                float x = v[j] * sm[p];
                unsigned short hb = f2bf(x);
                a_hi[q][j] = (short)hb;
                a_lo[q][j] = (short)f2bf(x - bf2f(hb));
            }
        }
#pragma unroll
        for (int q = 0; q < CHK; ++q) {
            const int kk = ch * CHK + q;
            if (kk < NKK2) {
#pragma unroll
                for (int c = 0; c < 5; ++c) {
                    const int ct = wv + 4 * c;
                    if (ct < NCT) {
                        bf16x8 bh = WH[(kk * NCT + ct) * 64 + lane];
                        bf16x8 bl = WL[(kk * NCT + ct) * 64 + lane];
                        acc[c] = __builtin_amdgcn_mfma_f32_16x16x32_bf16(a_hi[q], bh, acc[c], 0, 0, 0);
                        acc[c] = __builtin_amdgcn_mfma_f32_16x16x32_bf16(a_lo[q], bh, acc[c], 0, 0, 0);
                        acc[c] = __builtin_amdgcn_mfma_f32_16x16x32_bf16(a_hi[q], bl, acc[c], 0, 0, 0);
                    }
                }
            }
        }
    }

    float rs0 = 0.f, rs1 = 0.f, rs2 = 0.f, rs3 = 0.f;
#pragma unroll
    for (int c = 0; c < 5; ++c) {
        const int ct = wv + 4 * c;
        if (ct < NCT) {
            const int k  = ct * 16 + lrow;
            const bool ok = k < HH;
            const int kc = ok ? k : (HH - 1);
            const float iv  = instr[b * HH + kc];
            const float wsv = ok ? w_state[kc] : 0.f;
            rs0 += eluf(acc[c][0] * iv) * wsv;
            rs1 += eluf(acc[c][1] * iv) * wsv;
            rs2 += eluf(acc[c][2] * iv) * wsv;
            rs3 += eluf(acc[c][3] * iv) * wsv;
        }
    }
#pragma unroll
    for (int msk = 1; msk < 16; msk <<= 1) {
        rs0 += __shfl_xor(rs0, msk);
        rs1 += __shfl_xor(rs1, msk);
        rs2 += __shfl_xor(rs2, msk);
        rs3 += __shfl_xor(rs3, msk);
    }
    if (lrow == 0) {
        red[wv][lgrp * 4 + 0] = rs0;
        red[wv][lgrp * 4 + 1] = rs1;
        red[wv][lgrp * 4 + 2] = rs2;
        red[wv][lgrp * 4 + 3] = rs3;
    }
    __syncthreads();
    if (tid < 16) {
        const int n = nt * 16 + tid;
        float v = red[0][tid] + red[1][tid] + red[2][tid] + red[3][tid];
        state_logits[b * NN + n] = v + node_mask[b * NN + n];
    }
}

// ---------------------------------------------------------------------------
// Fallback fp32 node path (used only if ws_size can't hold W_np fragments).
// ---------------------------------------------------------------------------
extern "C" __global__ __launch_bounds__(256)
void node_kernel(const float* __restrict__ node_attr,
                 const float* __restrict__ instr,
                 const float* __restrict__ sim,
                 const float* __restrict__ node_mask,
                 const float* __restrict__ w_np,
                 const float* __restrict__ w_state,
                 float* __restrict__ state_logits)
{
    __shared__ float As[8 * 1200];
    const int b   = (int)blockIdx.x >> 3;
    const int n0  = ((int)blockIdx.x & 7) * 8;
    const int tid = (int)threadIdx.x;
    const int tx  = tid & 31;
    const int r   = tid >> 5;

    {
        const float4* src = reinterpret_cast<const float4*>(
            node_attr + (size_t)(b * NN + n0) * (PP * HH));
        float4* dst = reinterpret_cast<float4*>(As);
#pragma unroll 1
        for (int i = tid; i < 8 * 1200 / 4; i += 256) {
            float4 v = src[i];
            int p = (i % 300) / 75;
            float s = sim[b * PP + p];
            v.x *= s; v.y *= s; v.z *= s; v.w *= s;
            dst[i] = v;
        }
    }
    __syncthreads();

    float spart = 0.f;
    const float4* A4 = reinterpret_cast<const float4*>(As) + r * 300;

#pragma unroll 1
    for (int ct = 0; ct < 3; ++ct) {
        int k0 = ct * 128 + (tx << 2);
        if (k0 + 3 >= HH) continue;
        float acc0 = 0.f, acc1 = 0.f, acc2 = 0.f, acc3 = 0.f;
#pragma unroll 2
        for (int hq = 0; hq < 300; ++hq) {
            float4 a = A4[hq];
            const float* wb = w_np + (size_t)(hq * 4) * HH + k0;
            float4 w0 = *reinterpret_cast<const float4*>(wb);
            float4 w1 = *reinterpret_cast<const float4*>(wb + HH);
            float4 w2 = *reinterpret_cast<const float4*>(wb + 2 * HH);
            float4 w3 = *reinterpret_cast<const float4*>(wb + 3 * HH);
            acc0 = fmaf(a.x, w0.x, fmaf(a.y, w1.x, fmaf(a.z, w2.x, fmaf(a.w, w3.x, acc0))));
            acc1 = fmaf(a.x, w0.y, fmaf(a.y, w1.y, fmaf(a.z, w2.y, fmaf(a.w, w3.y, acc1))));
            acc2 = fmaf(a.x, w0.z, fmaf(a.y, w1.z, fmaf(a.z, w2.z, fmaf(a.w, w3.z, acc2))));
            acc3 = fmaf(a.x, w0.w, fmaf(a.y, w1.w, fmaf(a.z, w2.w, fmaf(a.w, w3.w, acc3))));
        }
        float4 iv  = *reinterpret_cast<const float4*>(instr + b * HH + k0);
        float4 wsv = *reinterpret_cast<const float4*>(w_state + k0);
        spart += eluf(acc0 * iv.x) * wsv.x + eluf(acc1 * iv.y) * wsv.y +
                 eluf(acc2 * iv.z) * wsv.z + eluf(acc3 * iv.w) * wsv.w;
    }

#pragma unroll
    for (int msk = 1; msk < 32; msk <<= 1) spart += __shfl_xor(spart, msk);
    if (tx == 0)
        state_logits[b * NN + n0 + r] = spart + node_mask[b * NN + n0 + r];
}

// ---------------------------------------------------------------------------
// Final: softmax both logit sets over n (one wave per b) and blend.
// ---------------------------------------------------------------------------
extern "C" __global__ __launch_bounds__(64)
void final_kernel(const float* __restrict__ rel_logits,
                  const float* __restrict__ state_logits,
                  const float* __restrict__ rel_sim,
                  float* __restrict__ out)
{
    const int b = (int)blockIdx.x;
    const int n = (int)threadIdx.x;
    float sl = state_logits[b * NN + n];
    float rl = rel_logits[b * NN + n];

    float ms = sl, mr = rl;
#pragma unroll
    for (int msk = 1; msk < 64; msk <<= 1) {
        ms = fmaxf(ms, __shfl_xor(ms, msk));
        mr = fmaxf(mr, __shfl_xor(mr, msk));
    }
    float es = __expf(sl - ms);
    float er = __expf(rl - mr);
    float ss = es, sr = er;
#pragma unroll
    for (int msk = 1; msk < 64; msk <<= 1) {
        ss += __shfl_xor(ss, msk);
        sr += __shfl_xor(sr, msk);
    }
    float rr = rel_sim[b];
    out[b * NN + n] = rr * (er / sr) + (1.f - rr) * (es / ss);
}

extern "C" void kernel_launch(void* const* d_in, const int* in_sizes, int n_in,
                              void* d_out, int out_size, void* d_ws, size_t ws_size,
                              hipStream_t stream) {
    const float* node_attr    = (const float*)d_in[0];
    const float* edge_attr    = (const float*)d_in[1];
    const float* instruction  = (const float*)d_in[2];
    const float* distribution = (const float*)d_in[3];
    const float* node_sim     = (const float*)d_in[4];
    const float* rel_sim      = (const float*)d_in[5];
    const float* node_mask    = (const float*)d_in[6];
    const float* w_np         = (const float*)d_in[7];
    const float* w_edge       = (const float*)d_in[8];
    const float* w_state      = (const float*)d_in[9];
    const float* w_rel        = (const float*)d_in[10];
    float* out = (float*)d_out;

    // workspace layout
    float* rel_ws   = (float*)d_ws;                          // [2048] f32
    float* state_ws = rel_ws + BB * NN;                      // [2048] f32
    char*  wsb      = (char*)d_ws;
    const size_t edge_frag = (size_t)NKK * NCT * 64 * 8 * 2; // 194,560 B each
    const size_t node_frag = (size_t)NKK2 * NCT * 64 * 8 * 2;// 739,328 B each
    short* w_hi  = (short*)(wsb + 16384);
    short* w_lo  = (short*)(wsb + 16384 + edge_frag);
    short* w2_hi = (short*)(wsb + 16384 + 2 * edge_frag);
    short* w2_lo = (short*)(wsb + 16384 + 2 * edge_frag + node_frag);
    const size_t need = 16384 + 2 * edge_frag + 2 * node_frag;
    const bool node_mfma_ok = (ws_size >= need);

    wprep_kernel<<<dim3(NKK * NCT), dim3(64), 0, stream>>>(w_edge, w_hi, w_lo);

    edge_kernel<<<dim3(BB * NN), dim3(256), 0, stream>>>(
        edge_attr, instruction, distribution, node_mask, w_hi, w_lo, w_rel, rel_ws);

    if (node_mfma_ok) {
        wprep2_kernel<<<dim3(NKK2 * NCT), dim3(64), 0, stream>>>(w_np, w2_hi, w2_lo);
        node_mfma_kernel<<<dim3(BB * 4), dim3(256), 0, stream>>>(
            node_attr, instruction, node_sim, node_mask, w2_hi, w2_lo,
            w_state, state_ws);
    } else {
        node_kernel<<<dim3(BB * 8), dim3(256), 0, stream>>>(
            node_attr, instruction, node_sim, node_mask, w_np, w_state, state_ws);
    }

    final_kernel<<<dim3(BB), dim3(64), 0, stream>>>(
        rel_ws, state_ws, rel_sim, out);
}

// Round 4
// 209.507 us; speedup vs baseline: 4.4257x; 1.2450x over previous
//
#include <hip/hip_runtime.h>
#include <math.h>

#define BB 32
#define NN 64
#define PP 4
#define HH 300

#define NKK 10    // edge reduction tiles: ceil(300/32)
#define NCT 19    // output col-tiles of 16: ceil(300/16)
#define NKK2 38   // node reduction tiles: ceil(1200/32)
#define CHK 10    // node kk chunk size (4 chunks cover 38)

typedef float f32x4  __attribute__((ext_vector_type(4)));
typedef short bf16x8 __attribute__((ext_vector_type(8)));

__device__ __forceinline__ float eluf(float x) {
    return x > 0.0f ? x : (__expf(x) - 1.0f);
}

// round-to-nearest-even fp32 -> bf16 bits
__device__ __forceinline__ unsigned short f2bf(float x) {
    unsigned u = __float_as_uint(x);
    u += 0x7FFFu + ((u >> 16) & 1u);
    return (unsigned short)(u >> 16);
}
__device__ __forceinline__ float bf2f(unsigned short s) {
    return __uint_as_float(((unsigned)s) << 16);
}

// ---------------------------------------------------------------------------
// Pre-convert W_edge (300x300 fp32) into MFMA B-fragment-linear bf16 (hi only;
// 2-pass split keeps A fp32-grade, B rounded to bf16):
// tile (kk, ct): lane l, elem j holds W[h][k], h = kk*32 + (l>>4)*8 + j,
// k = ct*16 + (l&15); zero-padded outside 300.
// ---------------------------------------------------------------------------
extern "C" __global__ __launch_bounds__(64)
void wprep_kernel(const float* __restrict__ w_edge,
                  short* __restrict__ w_hi)
{
    const int tile = (int)blockIdx.x;          // kk*NCT + ct
    const int kk = tile / NCT, ct = tile % NCT;
    const int lane = (int)threadIdx.x;
    const int h0 = kk * 32 + (lane >> 4) * 8;
    const int k  = ct * 16 + (lane & 15);
    const size_t base = ((size_t)tile * 64 + lane) * 8;
#pragma unroll
    for (int j = 0; j < 8; ++j) {
        int h = h0 + j;
        float v = (h < HH && k < HH) ? w_edge[h * HH + k] : 0.f;
        w_hi[base + j] = (short)f2bf(v);
    }
}

// Same for W_np flattened to 1200x300 (K index = p*300+h).
extern "C" __global__ __launch_bounds__(64)
void wprep2_kernel(const float* __restrict__ w_np,
                   short* __restrict__ w2_hi)
{
    const int tile = (int)blockIdx.x;          // kk*NCT + ct
    const int kk = tile / NCT, ct = tile % NCT;
    const int lane = (int)threadIdx.x;
    const int h0 = kk * 32 + (lane >> 4) * 8;
    const int k  = ct * 16 + (lane & 15);
    const size_t base = ((size_t)tile * 64 + lane) * 8;
#pragma unroll
    for (int j = 0; j < 8; ++j) {
        int h = h0 + j;
        float v = (h < PP * HH && k < HH) ? w_np[(size_t)h * HH + k] : 0.f;
        w2_hi[base + j] = (short)f2bf(v);
    }
}

// ---------------------------------------------------------------------------
// Edge path via MFMA, 2-pass bf16 split (A fp32-grade, B bf16).
// One block per (b,m); wave wv owns n-rows [16wv,16wv+16).
// B-fragments are LDS-staged per col-tile (shared by all 4 waves),
// double-buffered: issue loads(ct+1) -> compute(ct) -> ds_write -> barrier.
// ---------------------------------------------------------------------------
extern "C" __global__ __launch_bounds__(256, 4)
void edge_kernel(const float* __restrict__ edge_attr,
                 const float* __restrict__ instr,
                 const float* __restrict__ dist,
                 const float* __restrict__ node_mask,
                 const short* __restrict__ w_hi,
                 const float* __restrict__ w_rel,
                 float* __restrict__ rel_logits)
{
    __shared__ short Bs[2][NKK * 512];   // 2 x 10 KB, tile kk at [kk*512]
    __shared__ float red[NN];
    const int b    = (int)blockIdx.x / NN;
    const int m    = (int)blockIdx.x % NN;
    const int tid  = (int)threadIdx.x;
    const int wv   = tid >> 6;
    const int lane = tid & 63;
    const int lrow = lane & 15;
    const int lgrp = lane >> 4;

    // ---- A fragments (hi/lo) into registers, read-once from global ----
    const float* arow = edge_attr
        + (size_t)((b * NN + m) * NN + wv * 16 + lrow) * HH;
    bf16x8 a_hi[NKK], a_lo[NKK];
#pragma unroll
    for (int kk = 0; kk < NKK; ++kk) {
        const int h0 = kk * 32 + lgrp * 8;
        float v[8];
        if (h0 + 7 < HH) {
            f32x4 p0 = *reinterpret_cast<const f32x4*>(arow + h0);
            f32x4 p1 = *reinterpret_cast<const f32x4*>(arow + h0 + 4);
            v[0] = p0[0]; v[1] = p0[1]; v[2] = p0[2]; v[3] = p0[3];
            v[4] = p1[0]; v[5] = p1[1]; v[6] = p1[2]; v[7] = p1[3];
        } else {
#pragma unroll
            for (int j = 0; j < 8; ++j)
                v[j] = (h0 + j < HH) ? arow[h0 + j] : 0.f;
        }
#pragma unroll
        for (int j = 0; j < 8; ++j) {
            unsigned short hb = f2bf(v[j]);
            a_hi[kk][j] = (short)hb;
            a_lo[kk][j] = (short)f2bf(v[j] - bf2f(hb));
        }
    }

    const bf16x8* WH = reinterpret_cast<const bf16x8*>(w_hi);
    const int binst = b * HH;

    // staging: wave wv owns tiles kk = wv, wv+4, wv+8
    bf16x8 st[3];

    // prologue: stage ct=0 into buf 0
#pragma unroll
    for (int i = 0; i < 3; ++i) {
        const int kk = wv + 4 * i;
        if (kk < NKK) st[i] = WH[(kk * NCT + 0) * 64 + lane];
    }
#pragma unroll
    for (int i = 0; i < 3; ++i) {
        const int kk = wv + 4 * i;
        if (kk < NKK)
            *reinterpret_cast<bf16x8*>(&Bs[0][kk * 512 + lane * 8]) = st[i];
    }
    __syncthreads();

    float rs0 = 0.f, rs1 = 0.f, rs2 = 0.f, rs3 = 0.f;
    int cur = 0;

#pragma unroll 1
    for (int ct = 0; ct < NCT; ++ct) {
        // issue next tile's loads early
        if (ct + 1 < NCT) {
#pragma unroll
            for (int i = 0; i < 3; ++i) {
                const int kk = wv + 4 * i;
                if (kk < NKK) st[i] = WH[(kk * NCT + ct + 1) * 64 + lane];
            }
        }

        // compute current tile from LDS
        f32x4 acc = {0.f, 0.f, 0.f, 0.f};
#pragma unroll
        for (int kk = 0; kk < NKK; ++kk) {
            bf16x8 bh = *reinterpret_cast<const bf16x8*>(
                &Bs[cur][kk * 512 + lane * 8]);
            acc = __builtin_amdgcn_mfma_f32_16x16x32_bf16(a_hi[kk], bh, acc, 0, 0, 0);
            acc = __builtin_amdgcn_mfma_f32_16x16x32_bf16(a_lo[kk], bh, acc, 0, 0, 0);
        }

        // fused epilogue: col k = ct*16 + lrow, rows = lgrp*4 + i
        const int k  = ct * 16 + lrow;
        const bool ok = k < HH;
        const int kc = ok ? k : (HH - 1);
        const float iv = instr[binst + kc];
        const float wr = ok ? w_rel[kc] : 0.f;
        rs0 += eluf(acc[0] * iv) * wr;
        rs1 += eluf(acc[1] * iv) * wr;
        rs2 += eluf(acc[2] * iv) * wr;
        rs3 += eluf(acc[3] * iv) * wr;

        // write next tile into the other buffer
        if (ct + 1 < NCT) {
#pragma unroll
            for (int i = 0; i < 3; ++i) {
                const int kk = wv + 4 * i;
                if (kk < NKK)
                    *reinterpret_cast<bf16x8*>(
                        &Bs[cur ^ 1][kk * 512 + lane * 8]) = st[i];
            }
            __syncthreads();
        }
        cur ^= 1;
    }

#pragma unroll
    for (int msk = 1; msk < 16; msk <<= 1) {
        rs0 += __shfl_xor(rs0, msk);
        rs1 += __shfl_xor(rs1, msk);
        rs2 += __shfl_xor(rs2, msk);
        rs3 += __shfl_xor(rs3, msk);
    }
    if (lrow == 0) {
        const int r0 = wv * 16 + lgrp * 4;
        red[r0 + 0] = rs0;
        red[r0 + 1] = rs1;
        red[r0 + 2] = rs2;
        red[r0 + 3] = rs3;
    }
    __syncthreads();
    if (tid < 64) {
        float v = red[tid] * dist[b * NN + tid];
#pragma unroll
        for (int msk = 1; msk < 64; msk <<= 1) v += __shfl_xor(v, msk);
        if (tid == 0) rel_logits[b * NN + m] = v + node_mask[b * NN + m];
    }
}

// ---------------------------------------------------------------------------
// Node path via MFMA (2-pass): A[b,n,K=1200] (sim folded) @ Wflat[1200x300].
// One block per (b, 16-row n-tile); 4 waves split the 19 col-tiles.
// ---------------------------------------------------------------------------
extern "C" __global__ __launch_bounds__(256)
void node_mfma_kernel(const float* __restrict__ node_attr,
                      const float* __restrict__ instr,
                      const float* __restrict__ sim,
                      const float* __restrict__ node_mask,
                      const short* __restrict__ w2_hi,
                      const float* __restrict__ w_state,
                      float* __restrict__ state_logits)
{
    __shared__ float red[4][16];
    const int b    = (int)blockIdx.x >> 2;
    const int nt   = (int)blockIdx.x & 3;
    const int tid  = (int)threadIdx.x;
    const int wv   = tid >> 6;
    const int lane = tid & 63;
    const int lrow = lane & 15;
    const int lgrp = lane >> 4;

    const float* arow = node_attr
        + (size_t)(b * NN + nt * 16 + lrow) * (PP * HH);
    float sm[PP];
#pragma unroll
    for (int p = 0; p < PP; ++p) sm[p] = sim[b * PP + p];

    const bf16x8* WH = reinterpret_cast<const bf16x8*>(w2_hi);

    f32x4 acc[5] = {{0.f,0.f,0.f,0.f},{0.f,0.f,0.f,0.f},{0.f,0.f,0.f,0.f},
                    {0.f,0.f,0.f,0.f},{0.f,0.f,0.f,0.f}};

#pragma unroll 1
    for (int ch = 0; ch < 4; ++ch) {
        bf16x8 a_hi[CHK], a_lo[CHK];
#pragma unroll
        for (int q = 0; q < CHK; ++q) {
            const int kk = ch * CHK + q;
            const int h0 = kk * 32 + lgrp * 8;
            float v[8];
            if (kk < NKK2 && h0 + 7 < PP * HH) {
                f32x4 p0 = *reinterpret_cast<const f32x4*>(arow + h0);
                f32x4 p1 = *reinterpret_cast<const f32x4*>(arow + h0 + 4);
                v[0] = p0[0]; v[1] = p0[1]; v[2] = p0[2]; v[3] = p0[3];
                v[4] = p1[0]; v[5] = p1[1]; v[6] = p1[2]; v[7] = p1[3];
            } else {
#pragma unroll
                for (int j = 0; j < 8; ++j)
                    v[j] = (kk < NKK2 && h0 + j < PP * HH) ? arow[h0 + j] : 0.f;
            }
#pragma unroll
            for (int j = 0; j < 8; ++j) {
                const int h = h0 + j;
                const int p = (h < PP * HH) ? (h / HH) : 0;
                float x = v[j] * sm[p];
                unsigned short hb = f2bf(x);
                a_hi[q][j] = (short)hb;
                a_lo[q][j] = (short)f2bf(x - bf2f(hb));
            }
        }
#pragma unroll
        for (int q = 0; q < CHK; ++q) {
            const int kk = ch * CHK + q;
            if (kk < NKK2) {
#pragma unroll
                for (int c = 0; c < 5; ++c) {
                    const int ct = wv + 4 * c;
                    if (ct < NCT) {
                        bf16x8 bh = WH[(kk * NCT + ct) * 64 + lane];
                        acc[c] = __builtin_amdgcn_mfma_f32_16x16x32_bf16(a_hi[q], bh, acc[c], 0, 0, 0);
                        acc[c] = __builtin_amdgcn_mfma_f32_16x16x32_bf16(a_lo[q], bh, acc[c], 0, 0, 0);
                    }
                }
            }
        }
    }

    float rs0 = 0.f, rs1 = 0.f, rs2 = 0.f, rs3 = 0.f;
#pragma unroll
    for (int c = 0; c < 5; ++c) {
        const int ct = wv + 4 * c;
        if (ct < NCT) {
            const int k  = ct * 16 + lrow;
            const bool ok = k < HH;
            const int kc = ok ? k : (HH - 1);
            const float iv  = instr[b * HH + kc];
            const float wsv = ok ? w_state[kc] : 0.f;
            rs0 += eluf(acc[c][0] * iv) * wsv;
            rs1 += eluf(acc[c][1] * iv) * wsv;
            rs2 += eluf(acc[c][2] * iv) * wsv;
            rs3 += eluf(acc[c][3] * iv) * wsv;
        }
    }
#pragma unroll
    for (int msk = 1; msk < 16; msk <<= 1) {
        rs0 += __shfl_xor(rs0, msk);
        rs1 += __shfl_xor(rs1, msk);
        rs2 += __shfl_xor(rs2, msk);
        rs3 += __shfl_xor(rs3, msk);
    }
    if (lrow == 0) {
        red[wv][lgrp * 4 + 0] = rs0;
        red[wv][lgrp * 4 + 1] = rs1;
        red[wv][lgrp * 4 + 2] = rs2;
        red[wv][lgrp * 4 + 3] = rs3;
    }
    __syncthreads();
    if (tid < 16) {
        const int n = nt * 16 + tid;
        float v = red[0][tid] + red[1][tid] + red[2][tid] + red[3][tid];
        state_logits[b * NN + n] = v + node_mask[b * NN + n];
    }
}

// ---------------------------------------------------------------------------
// Fallback fp32 node path (used only if ws_size can't hold W_np fragments).
// ---------------------------------------------------------------------------
extern "C" __global__ __launch_bounds__(256)
void node_kernel(const float* __restrict__ node_attr,
                 const float* __restrict__ instr,
                 const float* __restrict__ sim,
                 const float* __restrict__ node_mask,
                 const float* __restrict__ w_np,
                 const float* __restrict__ w_state,
                 float* __restrict__ state_logits)
{
    __shared__ float As[8 * 1200];
    const int b   = (int)blockIdx.x >> 3;
    const int n0  = ((int)blockIdx.x & 7) * 8;
    const int tid = (int)threadIdx.x;
    const int tx  = tid & 31;
    const int r   = tid >> 5;

    {
        const float4* src = reinterpret_cast<const float4*>(
            node_attr + (size_t)(b * NN + n0) * (PP * HH));
        float4* dst = reinterpret_cast<float4*>(As);
#pragma unroll 1
        for (int i = tid; i < 8 * 1200 / 4; i += 256) {
            float4 v = src[i];
            int p = (i % 300) / 75;
            float s = sim[b * PP + p];
            v.x *= s; v.y *= s; v.z *= s; v.w *= s;
            dst[i] = v;
        }
    }
    __syncthreads();

    float spart = 0.f;
    const float4* A4 = reinterpret_cast<const float4*>(As) + r * 300;

#pragma unroll 1
    for (int ct = 0; ct < 3; ++ct) {
        int k0 = ct * 128 + (tx << 2);
        if (k0 + 3 >= HH) continue;
        float acc0 = 0.f, acc1 = 0.f, acc2 = 0.f, acc3 = 0.f;
#pragma unroll 2
        for (int hq = 0; hq < 300; ++hq) {
            float4 a = A4[hq];
            const float* wb = w_np + (size_t)(hq * 4) * HH + k0;
            float4 w0 = *reinterpret_cast<const float4*>(wb);
            float4 w1 = *reinterpret_cast<const float4*>(wb + HH);
            float4 w2 = *reinterpret_cast<const float4*>(wb + 2 * HH);
            float4 w3 = *reinterpret_cast<const float4*>(wb + 3 * HH);
            acc0 = fmaf(a.x, w0.x, fmaf(a.y, w1.x, fmaf(a.z, w2.x, fmaf(a.w, w3.x, acc0))));
            acc1 = fmaf(a.x, w0.y, fmaf(a.y, w1.y, fmaf(a.z, w2.y, fmaf(a.w, w3.y, acc1))));
            acc2 = fmaf(a.x, w0.z, fmaf(a.y, w1.z, fmaf(a.z, w2.z, fmaf(a.w, w3.z, acc2))));
            acc3 = fmaf(a.x, w0.w, fmaf(a.y, w1.w, fmaf(a.z, w2.w, fmaf(a.w, w3.w, acc3))));
        }
        float4 iv  = *reinterpret_cast<const float4*>(instr + b * HH + k0);
        float4 wsv = *reinterpret_cast<const float4*>(w_state + k0);
        spart += eluf(acc0 * iv.x) * wsv.x + eluf(acc1 * iv.y) * wsv.y +
                 eluf(acc2 * iv.z) * wsv.z + eluf(acc3 * iv.w) * wsv.w;
    }

#pragma unroll
    for (int msk = 1; msk < 32; msk <<= 1) spart += __shfl_xor(spart, msk);
    if (tx == 0)
        state_logits[b * NN + n0 + r] = spart + node_mask[b * NN + n0 + r];
}

// ---------------------------------------------------------------------------
// Final: softmax both logit sets over n (one wave per b) and blend.
// ---------------------------------------------------------------------------
extern "C" __global__ __launch_bounds__(64)
void final_kernel(const float* __restrict__ rel_logits,
                  const float* __restrict__ state_logits,
                  const float* __restrict__ rel_sim,
                  float* __restrict__ out)
{
    const int b = (int)blockIdx.x;
    const int n = (int)threadIdx.x;
    float sl = state_logits[b * NN + n];
    float rl = rel_logits[b * NN + n];

    float ms = sl, mr = rl;
#pragma unroll
    for (int msk = 1; msk < 64; msk <<= 1) {
        ms = fmaxf(ms, __shfl_xor(ms, msk));
        mr = fmaxf(mr, __shfl_xor(mr, msk));
    }
    float es = __expf(sl - ms);
    float er = __expf(rl - mr);
    float ss = es, sr = er;
#pragma unroll
    for (int msk = 1; msk < 64; msk <<= 1) {
        ss += __shfl_xor(ss, msk);
        sr += __shfl_xor(sr, msk);
    }
    float rr = rel_sim[b];
    out[b * NN + n] = rr * (er / sr) + (1.f - rr) * (es / ss);
}

extern "C" void kernel_launch(void* const* d_in, const int* in_sizes, int n_in,
                              void* d_out, int out_size, void* d_ws, size_t ws_size,
                              hipStream_t stream) {
    const float* node_attr    = (const float*)d_in[0];
    const float* edge_attr    = (const float*)d_in[1];
    const float* instruction  = (const float*)d_in[2];
    const float* distribution = (const float*)d_in[3];
    const float* node_sim     = (const float*)d_in[4];
    const float* rel_sim      = (const float*)d_in[5];
    const float* node_mask    = (const float*)d_in[6];
    const float* w_np         = (const float*)d_in[7];
    const float* w_edge       = (const float*)d_in[8];
    const float* w_state      = (const float*)d_in[9];
    const float* w_rel        = (const float*)d_in[10];
    float* out = (float*)d_out;

    // workspace layout
    float* rel_ws   = (float*)d_ws;                          // [2048] f32
    float* state_ws = rel_ws + BB * NN;                      // [2048] f32
    char*  wsb      = (char*)d_ws;
    const size_t edge_frag = (size_t)NKK * NCT * 64 * 8 * 2;   // 194,560 B
    const size_t node_frag = (size_t)NKK2 * NCT * 64 * 8 * 2;  // 739,328 B
    short* w_hi  = (short*)(wsb + 16384);
    short* w2_hi = (short*)(wsb + 16384 + edge_frag);
    const size_t need = 16384 + edge_frag + node_frag;
    const bool node_mfma_ok = (ws_size >= need);

    wprep_kernel<<<dim3(NKK * NCT), dim3(64), 0, stream>>>(w_edge, w_hi);

    edge_kernel<<<dim3(BB * NN), dim3(256), 0, stream>>>(
        edge_attr, instruction, distribution, node_mask, w_hi, w_rel, rel_ws);

    if (node_mfma_ok) {
        wprep2_kernel<<<dim3(NKK2 * NCT), dim3(64), 0, stream>>>(w_np, w2_hi);
        node_mfma_kernel<<<dim3(BB * 4), dim3(256), 0, stream>>>(
            node_attr, instruction, node_sim, node_mask, w2_hi,
            w_state, state_ws);
    } else {
        node_kernel<<<dim3(BB * 8), dim3(256), 0, stream>>>(
            node_attr, instruction, node_sim, node_mask, w_np, w_state, state_ws);
    }

    final_kernel<<<dim3(BB), dim3(64), 0, stream>>>(
        rel_ws, state_ws, rel_sim, out);
}

// Round 5
// 158.208 us; speedup vs baseline: 5.8608x; 1.3242x over previous
//
#include <hip/hip_runtime.h>
#include <math.h>

#define BB 32
#define NN 64
#define PP 4
#define HH 300

#define NKK 10    // edge reduction tiles: ceil(300/32)
#define NCT 19    // output col-tiles of 16: ceil(300/16)
#define NKK2 38   // node reduction tiles: ceil(1200/32)
#define CHK 10    // node kk chunk size (4 chunks cover 38)

typedef float f32x4  __attribute__((ext_vector_type(4)));
typedef short bf16x8 __attribute__((ext_vector_type(8)));

__device__ __forceinline__ float eluf(float x) {
    return x > 0.0f ? x : (__expf(x) - 1.0f);
}

// round-to-nearest-even fp32 -> bf16 bits
__device__ __forceinline__ unsigned short f2bf(float x) {
    unsigned u = __float_as_uint(x);
    u += 0x7FFFu + ((u >> 16) & 1u);
    return (unsigned short)(u >> 16);
}
__device__ __forceinline__ float bf2f(unsigned short s) {
    return __uint_as_float(((unsigned)s) << 16);
}

// ---------------------------------------------------------------------------
// Pre-convert W_edge (300x300 fp32) into MFMA B-fragment-linear bf16 (hi only;
// 2-pass split keeps A fp32-grade, B rounded to bf16):
// tile (kk, ct): lane l, elem j holds W[h][k], h = kk*32 + (l>>4)*8 + j,
// k = ct*16 + (l&15); zero-padded outside 300.
// ---------------------------------------------------------------------------
extern "C" __global__ __launch_bounds__(64)
void wprep_kernel(const float* __restrict__ w_edge,
                  short* __restrict__ w_hi)
{
    const int tile = (int)blockIdx.x;          // kk*NCT + ct
    const int kk = tile / NCT, ct = tile % NCT;
    const int lane = (int)threadIdx.x;
    const int h0 = kk * 32 + (lane >> 4) * 8;
    const int k  = ct * 16 + (lane & 15);
    const size_t base = ((size_t)tile * 64 + lane) * 8;
#pragma unroll
    for (int j = 0; j < 8; ++j) {
        int h = h0 + j;
        float v = (h < HH && k < HH) ? w_edge[h * HH + k] : 0.f;
        w_hi[base + j] = (short)f2bf(v);
    }
}

// Same for W_np flattened to 1200x300 (K index = p*300+h).
extern "C" __global__ __launch_bounds__(64)
void wprep2_kernel(const float* __restrict__ w_np,
                   short* __restrict__ w2_hi)
{
    const int tile = (int)blockIdx.x;          // kk*NCT + ct
    const int kk = tile / NCT, ct = tile % NCT;
    const int lane = (int)threadIdx.x;
    const int h0 = kk * 32 + (lane >> 4) * 8;
    const int k  = ct * 16 + (lane & 15);
    const size_t base = ((size_t)tile * 64 + lane) * 8;
#pragma unroll
    for (int j = 0; j < 8; ++j) {
        int h = h0 + j;
        float v = (h < PP * HH && k < HH) ? w_np[(size_t)h * HH + k] : 0.f;
        w2_hi[base + j] = (short)f2bf(v);
    }
}

// ---------------------------------------------------------------------------
// Edge path via MFMA, 2-pass bf16 split (A fp32-grade, B bf16).
// One block per (b,m); wave wv owns n-rows [16wv,16wv+16).
// B-fragments are LDS-staged per col-tile (shared by all 4 waves),
// double-buffered: issue loads(ct+1) -> compute(ct) -> ds_write -> barrier.
// NOTE: no min-waves force in launch_bounds — round 4's (256,4) capped
// VGPR at 64 and spilled the 80-VGPR A-fragment set to scratch (180 MB
// of scratch writes per dispatch). Let the allocator keep A resident.
// ---------------------------------------------------------------------------
extern "C" __global__ __launch_bounds__(256)
void edge_kernel(const float* __restrict__ edge_attr,
                 const float* __restrict__ instr,
                 const float* __restrict__ dist,
                 const float* __restrict__ node_mask,
                 const short* __restrict__ w_hi,
                 const float* __restrict__ w_rel,
                 float* __restrict__ rel_logits)
{
    __shared__ short Bs[2][NKK * 512];   // 2 x 10 KB, tile kk at [kk*512]
    __shared__ float red[NN];
    const int b    = (int)blockIdx.x / NN;
    const int m    = (int)blockIdx.x % NN;
    const int tid  = (int)threadIdx.x;
    const int wv   = tid >> 6;
    const int lane = tid & 63;
    const int lrow = lane & 15;
    const int lgrp = lane >> 4;

    // ---- A fragments (hi/lo) into registers, read-once from global ----
    const float* arow = edge_attr
        + (size_t)((b * NN + m) * NN + wv * 16 + lrow) * HH;
    bf16x8 a_hi[NKK], a_lo[NKK];
#pragma unroll
    for (int kk = 0; kk < NKK; ++kk) {
        const int h0 = kk * 32 + lgrp * 8;
        float v[8];
        if (h0 + 7 < HH) {
            f32x4 p0 = *reinterpret_cast<const f32x4*>(arow + h0);
            f32x4 p1 = *reinterpret_cast<const f32x4*>(arow + h0 + 4);
            v[0] = p0[0]; v[1] = p0[1]; v[2] = p0[2]; v[3] = p0[3];
            v[4] = p1[0]; v[5] = p1[1]; v[6] = p1[2]; v[7] = p1[3];
        } else {
#pragma unroll
            for (int j = 0; j < 8; ++j)
                v[j] = (h0 + j < HH) ? arow[h0 + j] : 0.f;
        }
#pragma unroll
        for (int j = 0; j < 8; ++j) {
            unsigned short hb = f2bf(v[j]);
            a_hi[kk][j] = (short)hb;
            a_lo[kk][j] = (short)f2bf(v[j] - bf2f(hb));
        }
    }

    const bf16x8* WH = reinterpret_cast<const bf16x8*>(w_hi);
    const int binst = b * HH;

    // staging: wave wv owns tiles kk = wv, wv+4, wv+8
    bf16x8 st[3];

    // prologue: stage ct=0 into buf 0
#pragma unroll
    for (int i = 0; i < 3; ++i) {
        const int kk = wv + 4 * i;
        if (kk < NKK) st[i] = WH[(kk * NCT + 0) * 64 + lane];
    }
#pragma unroll
    for (int i = 0; i < 3; ++i) {
        const int kk = wv + 4 * i;
        if (kk < NKK)
            *reinterpret_cast<bf16x8*>(&Bs[0][kk * 512 + lane * 8]) = st[i];
    }
    __syncthreads();

    float rs0 = 0.f, rs1 = 0.f, rs2 = 0.f, rs3 = 0.f;
    int cur = 0;

#pragma unroll 1
    for (int ct = 0; ct < NCT; ++ct) {
        // issue next tile's loads early
        if (ct + 1 < NCT) {
#pragma unroll
            for (int i = 0; i < 3; ++i) {
                const int kk = wv + 4 * i;
                if (kk < NKK) st[i] = WH[(kk * NCT + ct + 1) * 64 + lane];
            }
        }

        // compute current tile from LDS
        f32x4 acc = {0.f, 0.f, 0.f, 0.f};
#pragma unroll
        for (int kk = 0; kk < NKK; ++kk) {
            bf16x8 bh = *reinterpret_cast<const bf16x8*>(
                &Bs[cur][kk * 512 + lane * 8]);
            acc = __builtin_amdgcn_mfma_f32_16x16x32_bf16(a_hi[kk], bh, acc, 0, 0, 0);
            acc = __builtin_amdgcn_mfma_f32_16x16x32_bf16(a_lo[kk], bh, acc, 0, 0, 0);
        }

        // fused epilogue: col k = ct*16 + lrow, rows = lgrp*4 + i
        const int k  = ct * 16 + lrow;
        const bool ok = k < HH;
        const int kc = ok ? k : (HH - 1);
        const float iv = instr[binst + kc];
        const float wr = ok ? w_rel[kc] : 0.f;
        rs0 += eluf(acc[0] * iv) * wr;
        rs1 += eluf(acc[1] * iv) * wr;
        rs2 += eluf(acc[2] * iv) * wr;
        rs3 += eluf(acc[3] * iv) * wr;

        // write next tile into the other buffer
        if (ct + 1 < NCT) {
#pragma unroll
            for (int i = 0; i < 3; ++i) {
                const int kk = wv + 4 * i;
                if (kk < NKK)
                    *reinterpret_cast<bf16x8*>(
                        &Bs[cur ^ 1][kk * 512 + lane * 8]) = st[i];
            }
            __syncthreads();
        }
        cur ^= 1;
    }

#pragma unroll
    for (int msk = 1; msk < 16; msk <<= 1) {
        rs0 += __shfl_xor(rs0, msk);
        rs1 += __shfl_xor(rs1, msk);
        rs2 += __shfl_xor(rs2, msk);
        rs3 += __shfl_xor(rs3, msk);
    }
    if (lrow == 0) {
        const int r0 = wv * 16 + lgrp * 4;
        red[r0 + 0] = rs0;
        red[r0 + 1] = rs1;
        red[r0 + 2] = rs2;
        red[r0 + 3] = rs3;
    }
    __syncthreads();
    if (tid < 64) {
        float v = red[tid] * dist[b * NN + tid];
#pragma unroll
        for (int msk = 1; msk < 64; msk <<= 1) v += __shfl_xor(v, msk);
        if (tid == 0) rel_logits[b * NN + m] = v + node_mask[b * NN + m];
    }
}

// ---------------------------------------------------------------------------
// Node path via MFMA (2-pass): A[b,n,K=1200] (sim folded) @ Wflat[1200x300].
// One block per (b, 16-row n-tile); 4 waves split the 19 col-tiles.
// ---------------------------------------------------------------------------
extern "C" __global__ __launch_bounds__(256)
void node_mfma_kernel(const float* __restrict__ node_attr,
                      const float* __restrict__ instr,
                      const float* __restrict__ sim,
                      const float* __restrict__ node_mask,
                      const short* __restrict__ w2_hi,
                      const float* __restrict__ w_state,
                      float* __restrict__ state_logits)
{
    __shared__ float red[4][16];
    const int b    = (int)blockIdx.x >> 2;
    const int nt   = (int)blockIdx.x & 3;
    const int tid  = (int)threadIdx.x;
    const int wv   = tid >> 6;
    const int lane = tid & 63;
    const int lrow = lane & 15;
    const int lgrp = lane >> 4;

    const float* arow = node_attr
        + (size_t)(b * NN + nt * 16 + lrow) * (PP * HH);
    float sm[PP];
#pragma unroll
    for (int p = 0; p < PP; ++p) sm[p] = sim[b * PP + p];

    const bf16x8* WH = reinterpret_cast<const bf16x8*>(w2_hi);

    f32x4 acc[5] = {{0.f,0.f,0.f,0.f},{0.f,0.f,0.f,0.f},{0.f,0.f,0.f,0.f},
                    {0.f,0.f,0.f,0.f},{0.f,0.f,0.f,0.f}};

#pragma unroll 1
    for (int ch = 0; ch < 4; ++ch) {
        bf16x8 a_hi[CHK], a_lo[CHK];
#pragma unroll
        for (int q = 0; q < CHK; ++q) {
            const int kk = ch * CHK + q;
            const int h0 = kk * 32 + lgrp * 8;
            float v[8];
            if (kk < NKK2 && h0 + 7 < PP * HH) {
                f32x4 p0 = *reinterpret_cast<const f32x4*>(arow + h0);
                f32x4 p1 = *reinterpret_cast<const f32x4*>(arow + h0 + 4);
                v[0] = p0[0]; v[1] = p0[1]; v[2] = p0[2]; v[3] = p0[3];
                v[4] = p1[0]; v[5] = p1[1]; v[6] = p1[2]; v[7] = p1[3];
            } else {
#pragma unroll
                for (int j = 0; j < 8; ++j)
                    v[j] = (kk < NKK2 && h0 + j < PP * HH) ? arow[h0 + j] : 0.f;
            }
#pragma unroll
            for (int j = 0; j < 8; ++j) {
                const int h = h0 + j;
                const int p = (h < PP * HH) ? (h / HH) : 0;
                float x = v[j] * sm[p];
                unsigned short hb = f2bf(x);
                a_hi[q][j] = (short)hb;
                a_lo[q][j] = (short)f2bf(x - bf2f(hb));
            }
        }
#pragma unroll
        for (int q = 0; q < CHK; ++q) {
            const int kk = ch * CHK + q;
            if (kk < NKK2) {
#pragma unroll
                for (int c = 0; c < 5; ++c) {
                    const int ct = wv + 4 * c;
                    if (ct < NCT) {
                        bf16x8 bh = WH[(kk * NCT + ct) * 64 + lane];
                        acc[c] = __builtin_amdgcn_mfma_f32_16x16x32_bf16(a_hi[q], bh, acc[c], 0, 0, 0);
                        acc[c] = __builtin_amdgcn_mfma_f32_16x16x32_bf16(a_lo[q], bh, acc[c], 0, 0, 0);
                    }
                }
            }
        }
    }

    float rs0 = 0.f, rs1 = 0.f, rs2 = 0.f, rs3 = 0.f;
#pragma unroll
    for (int c = 0; c < 5; ++c) {
        const int ct = wv + 4 * c;
        if (ct < NCT) {
            const int k  = ct * 16 + lrow;
            const bool ok = k < HH;
            const int kc = ok ? k : (HH - 1);
            const float iv  = instr[b * HH + kc];
            const float wsv = ok ? w_state[kc] : 0.f;
            rs0 += eluf(acc[c][0] * iv) * wsv;
            rs1 += eluf(acc[c][1] * iv) * wsv;
            rs2 += eluf(acc[c][2] * iv) * wsv;
            rs3 += eluf(acc[c][3] * iv) * wsv;
        }
    }
#pragma unroll
    for (int msk = 1; msk < 16; msk <<= 1) {
        rs0 += __shfl_xor(rs0, msk);
        rs1 += __shfl_xor(rs1, msk);
        rs2 += __shfl_xor(rs2, msk);
        rs3 += __shfl_xor(rs3, msk);
    }
    if (lrow == 0) {
        red[wv][lgrp * 4 + 0] = rs0;
        red[wv][lgrp * 4 + 1] = rs1;
        red[wv][lgrp * 4 + 2] = rs2;
        red[wv][lgrp * 4 + 3] = rs3;
    }
    __syncthreads();
    if (tid < 16) {
        const int n = nt * 16 + tid;
        float v = red[0][tid] + red[1][tid] + red[2][tid] + red[3][tid];
        state_logits[b * NN + n] = v + node_mask[b * NN + n];
    }
}

// ---------------------------------------------------------------------------
// Fallback fp32 node path (used only if ws_size can't hold W_np fragments).
// ---------------------------------------------------------------------------
extern "C" __global__ __launch_bounds__(256)
void node_kernel(const float* __restrict__ node_attr,
                 const float* __restrict__ instr,
                 const float* __restrict__ sim,
                 const float* __restrict__ node_mask,
                 const float* __restrict__ w_np,
                 const float* __restrict__ w_state,
                 float* __restrict__ state_logits)
{
    __shared__ float As[8 * 1200];
    const int b   = (int)blockIdx.x >> 3;
    const int n0  = ((int)blockIdx.x & 7) * 8;
    const int tid = (int)threadIdx.x;
    const int tx  = tid & 31;
    const int r   = tid >> 5;

    {
        const float4* src = reinterpret_cast<const float4*>(
            node_attr + (size_t)(b * NN + n0) * (PP * HH));
        float4* dst = reinterpret_cast<float4*>(As);
#pragma unroll 1
        for (int i = tid; i < 8 * 1200 / 4; i += 256) {
            float4 v = src[i];
            int p = (i % 300) / 75;
            float s = sim[b * PP + p];
            v.x *= s; v.y *= s; v.z *= s; v.w *= s;
            dst[i] = v;
        }
    }
    __syncthreads();

    float spart = 0.f;
    const float4* A4 = reinterpret_cast<const float4*>(As) + r * 300;

#pragma unroll 1
    for (int ct = 0; ct < 3; ++ct) {
        int k0 = ct * 128 + (tx << 2);
        if (k0 + 3 >= HH) continue;
        float acc0 = 0.f, acc1 = 0.f, acc2 = 0.f, acc3 = 0.f;
#pragma unroll 2
        for (int hq = 0; hq < 300; ++hq) {
            float4 a = A4[hq];
            const float* wb = w_np + (size_t)(hq * 4) * HH + k0;
            float4 w0 = *reinterpret_cast<const float4*>(wb);
            float4 w1 = *reinterpret_cast<const float4*>(wb + HH);
            float4 w2 = *reinterpret_cast<const float4*>(wb + 2 * HH);
            float4 w3 = *reinterpret_cast<const float4*>(wb + 3 * HH);
            acc0 = fmaf(a.x, w0.x, fmaf(a.y, w1.x, fmaf(a.z, w2.x, fmaf(a.w, w3.x, acc0))));
            acc1 = fmaf(a.x, w0.y, fmaf(a.y, w1.y, fmaf(a.z, w2.y, fmaf(a.w, w3.y, acc1))));
            acc2 = fmaf(a.x, w0.z, fmaf(a.y, w1.z, fmaf(a.z, w2.z, fmaf(a.w, w3.z, acc2))));
            acc3 = fmaf(a.x, w0.w, fmaf(a.y, w1.w, fmaf(a.z, w2.w, fmaf(a.w, w3.w, acc3))));
        }
        float4 iv  = *reinterpret_cast<const float4*>(instr + b * HH + k0);
        float4 wsv = *reinterpret_cast<const float4*>(w_state + k0);
        spart += eluf(acc0 * iv.x) * wsv.x + eluf(acc1 * iv.y) * wsv.y +
                 eluf(acc2 * iv.z) * wsv.z + eluf(acc3 * iv.w) * wsv.w;
    }

#pragma unroll
    for (int msk = 1; msk < 32; msk <<= 1) spart += __shfl_xor(spart, msk);
    if (tx == 0)
        state_logits[b * NN + n0 + r] = spart + node_mask[b * NN + n0 + r];
}

// ---------------------------------------------------------------------------
// Final: softmax both logit sets over n (one wave per b) and blend.
// ---------------------------------------------------------------------------
extern "C" __global__ __launch_bounds__(64)
void final_kernel(const float* __restrict__ rel_logits,
                  const float* __restrict__ state_logits,
                  const float* __restrict__ rel_sim,
                  float* __restrict__ out)
{
    const int b = (int)blockIdx.x;
    const int n = (int)threadIdx.x;
    float sl = state_logits[b * NN + n];
    float rl = rel_logits[b * NN + n];

    float ms = sl, mr = rl;
#pragma unroll
    for (int msk = 1; msk < 64; msk <<= 1) {
        ms = fmaxf(ms, __shfl_xor(ms, msk));
        mr = fmaxf(mr, __shfl_xor(mr, msk));
    }
    float es = __expf(sl - ms);
    float er = __expf(rl - mr);
    float ss = es, sr = er;
#pragma unroll
    for (int msk = 1; msk < 64; msk <<= 1) {
        ss += __shfl_xor(ss, msk);
        sr += __shfl_xor(sr, msk);
    }
    float rr = rel_sim[b];
    out[b * NN + n] = rr * (er / sr) + (1.f - rr) * (es / ss);
}

extern "C" void kernel_launch(void* const* d_in, const int* in_sizes, int n_in,
                              void* d_out, int out_size, void* d_ws, size_t ws_size,
                              hipStream_t stream) {
    const float* node_attr    = (const float*)d_in[0];
    const float* edge_attr    = (const float*)d_in[1];
    const float* instruction  = (const float*)d_in[2];
    const float* distribution = (const float*)d_in[3];
    const float* node_sim     = (const float*)d_in[4];
    const float* rel_sim      = (const float*)d_in[5];
    const float* node_mask    = (const float*)d_in[6];
    const float* w_np         = (const float*)d_in[7];
    const float* w_edge       = (const float*)d_in[8];
    const float* w_state      = (const float*)d_in[9];
    const float* w_rel        = (const float*)d_in[10];
    float* out = (float*)d_out;

    // workspace layout
    float* rel_ws   = (float*)d_ws;                          // [2048] f32
    float* state_ws = rel_ws + BB * NN;                      // [2048] f32
    char*  wsb      = (char*)d_ws;
    const size_t edge_frag = (size_t)NKK * NCT * 64 * 8 * 2;   // 194,560 B
    const size_t node_frag = (size_t)NKK2 * NCT * 64 * 8 * 2;  // 739,328 B
    short* w_hi  = (short*)(wsb + 16384);
    short* w2_hi = (short*)(wsb + 16384 + edge_frag);
    const size_t need = 16384 + edge_frag + node_frag;
    const bool node_mfma_ok = (ws_size >= need);

    wprep_kernel<<<dim3(NKK * NCT), dim3(64), 0, stream>>>(w_edge, w_hi);

    edge_kernel<<<dim3(BB * NN), dim3(256), 0, stream>>>(
        edge_attr, instruction, distribution, node_mask, w_hi, w_rel, rel_ws);

    if (node_mfma_ok) {
        wprep2_kernel<<<dim3(NKK2 * NCT), dim3(64), 0, stream>>>(w_np, w2_hi);
        node_mfma_kernel<<<dim3(BB * 4), dim3(256), 0, stream>>>(
            node_attr, instruction, node_sim, node_mask, w2_hi,
            w_state, state_ws);
    } else {
        node_kernel<<<dim3(BB * 8), dim3(256), 0, stream>>>(
            node_attr, instruction, node_sim, node_mask, w_np, w_state, state_ws);
    }

    final_kernel<<<dim3(BB), dim3(64), 0, stream>>>(
        rel_ws, state_ws, rel_sim, out);
}